// Round 21
// baseline (92.738 us; speedup 1.0000x reference)
//
#include <hip/hip_runtime.h>
#include <hip/hip_bf16.h>
#include <stdint.h>

#define B_SZ 4
#define T_SEQ 1024
#define E_DIM 1024
#define NH 16
#define HD 64
#define THREE_E 3072
#define NTOK 4096

typedef unsigned short u16;
typedef unsigned int u32;
using short8v = __attribute__((ext_vector_type(8))) short;
using short4v = __attribute__((ext_vector_type(4))) short;
using f32x4 = __attribute__((ext_vector_type(4))) float;

__device__ __forceinline__ u16 f2bf(float f) {
    union { float f; uint32_t u; } c; c.f = f;
    uint32_t u = c.u;
    uint32_t r = (u + 0x7FFFu + ((u >> 16) & 1u)) >> 16;
    return (u16)r;
}

__device__ __forceinline__ u32 cvt_pk_bf16(float lo, float hi) {
    u32 r;
    asm("v_cvt_pk_bf16_f32 %0, %1, %2" : "=v"(r) : "v"(lo), "v"(hi));
    return r;
}

__device__ __forceinline__ void gload_lds16(const u16* g, u16* l) {
    __builtin_amdgcn_global_load_lds((const __attribute__((address_space(1))) void*)g,
                                     (__attribute__((address_space(3))) void*)l, 16, 0, 0);
}

// ---------------- fused prep: RMSNorm (blocks 0..4095) + weight cast (4096..8191)
__global__ __launch_bounds__(256) void prep_kernel(const float* __restrict__ x,
                                                   const float* __restrict__ scale,
                                                   const float* __restrict__ wq,
                                                   const float* __restrict__ wp,
                                                   u16* __restrict__ xn,
                                                   u16* __restrict__ wqb,
                                                   u16* __restrict__ wpb) {
    int bx = blockIdx.x;
    int tid = threadIdx.x;
    if (bx < 4096) {
        int row = bx;
        const float4* xr = reinterpret_cast<const float4*>(x + (size_t)row * E_DIM);
        float4 v = xr[tid];
        float ss = v.x * v.x + v.y * v.y + v.z * v.z + v.w * v.w;
        for (int off = 32; off > 0; off >>= 1) ss += __shfl_xor(ss, off);
        __shared__ float red[4];
        if ((tid & 63) == 0) red[tid >> 6] = ss;
        __syncthreads();
        float total = red[0] + red[1] + red[2] + red[3];
        float rs = rsqrtf(total * (1.0f / E_DIM) + 1e-5f);
        float4 s = reinterpret_cast<const float4*>(scale)[tid];
        u16* o = xn + (size_t)row * E_DIM + tid * 4;
        o[0] = f2bf(v.x * rs * s.x);
        o[1] = f2bf(v.y * rs * s.y);
        o[2] = f2bf(v.z * rs * s.z);
        o[3] = f2bf(v.w * rs * s.w);
    } else {
        const int NQ = (THREE_E * E_DIM) / 4;
        const int NP = (E_DIM * E_DIM) / 4;
        int i = (bx - 4096) * 256 + tid;
        if (i < NQ) {
            float4 v = reinterpret_cast<const float4*>(wq)[i];
            u16* o = wqb + (size_t)i * 4;
            o[0] = f2bf(v.x); o[1] = f2bf(v.y); o[2] = f2bf(v.z); o[3] = f2bf(v.w);
        } else if (i < NQ + NP) {
            int j = i - NQ;
            float4 v = reinterpret_cast<const float4*>(wp)[j];
            u16* o = wpb + (size_t)j * 4;
            o[0] = f2bf(v.x); o[1] = f2bf(v.y); o[2] = f2bf(v.z); o[3] = f2bf(v.w);
        }
    }
}

// ---------------- 2-phase GEMM + T3-minimum async prefetch.
// Per iter: barrier(drains stage(t)); ds_reads(t); barrier(drains reads);
// stage(t+1) into SAME buffer (overlaps MFMA cluster); all MFMAs.
template <int BN, bool OUT_BF16>
__global__ __launch_bounds__(256) void gemm_lds_kernel(const u16* __restrict__ A,
                                                       const u16* __restrict__ Bw,
                                                       void* __restrict__ C,
                                                       int N, int K) {
    constexpr int NFR = BN / 32;
    __shared__ u16 As[128 * 64];
    __shared__ u16 Bs[BN * 64];
    int tid = threadIdx.x;
    int lane = tid & 63, wid = tid >> 6;
    int lq = lane & 15, lg = lane >> 4;

    int gx = gridDim.x;
    int nwg = gx * gridDim.y;
    int orig = blockIdx.y * gx + blockIdx.x;
    int cpx = nwg >> 3;
    int swz = (orig & 7) * cpx + (orig >> 3);
    int bx = swz % gx, by = swz / gx;
    int mblk = by * 128, nblk = bx * BN;

    int srowA = wid * 32 + (lane >> 3);
    int srowB = wid * (BN / 4) + (lane >> 3);
    int csw = ((lane & 7) ^ ((lane >> 3) & 7)) * 8;
    const u16* gA = A + (size_t)(mblk + srowA) * K + csw;
    const u16* gB = Bw + (size_t)(nblk + srowB) * K + csw;
    u16* lA = As + wid * 2048;
    u16* lB = Bs + wid * (BN / 4) * 64;

    f32x4 acc[4][NFR] = {};
    int m0w = (wid >> 1) * 64;
    int n0w = (wid & 1) * (BN / 2);
    int r7 = lq & 7;
    const int NT = K / 64;

#pragma unroll
    for (int i = 0; i < 4; ++i) gload_lds16(gA + (size_t)i * 8 * K, lA + i * 512);
#pragma unroll
    for (int i = 0; i < NFR; ++i) gload_lds16(gB + (size_t)i * 8 * K, lB + i * 512);

    for (int t = 0; t < NT; ++t) {
        __syncthreads();   // implicit vmcnt(0): stage(t) landed (all waves)
        short8v af[2][4], bf[2][NFR];
#pragma unroll
        for (int kk = 0; kk < 2; ++kk) {
#pragma unroll
            for (int mi = 0; mi < 4; ++mi)
                af[kk][mi] = *reinterpret_cast<const short8v*>(
                    &As[(m0w + mi * 16 + lq) * 64 + ((kk * 4 + lg) ^ r7) * 8]);
#pragma unroll
            for (int ni = 0; ni < NFR; ++ni)
                bf[kk][ni] = *reinterpret_cast<const short8v*>(
                    &Bs[(n0w + ni * 16 + lq) * 64 + ((kk * 4 + lg) ^ r7) * 8]);
        }
        __syncthreads();   // implicit lgkmcnt(0): all waves done reading tile t
        if (t + 1 < NT) {  // async stage of t+1 overlaps the MFMA cluster below
            int k0 = (t + 1) * 64;
#pragma unroll
            for (int i = 0; i < 4; ++i) gload_lds16(gA + k0 + (size_t)i * 8 * K, lA + i * 512);
#pragma unroll
            for (int i = 0; i < NFR; ++i) gload_lds16(gB + k0 + (size_t)i * 8 * K, lB + i * 512);
        }
        __builtin_amdgcn_sched_barrier(0);   // pin stage issue above the MFMAs
        __builtin_amdgcn_s_setprio(1);
#pragma unroll
        for (int mi = 0; mi < 4; ++mi)
#pragma unroll
            for (int ni = 0; ni < NFR; ++ni) {
                acc[mi][ni] = __builtin_amdgcn_mfma_f32_16x16x32_bf16(af[0][mi], bf[0][ni], acc[mi][ni], 0, 0, 0);
                acc[mi][ni] = __builtin_amdgcn_mfma_f32_16x16x32_bf16(af[1][mi], bf[1][ni], acc[mi][ni], 0, 0, 0);
            }
        __builtin_amdgcn_s_setprio(0);
    }
#pragma unroll
    for (int mi = 0; mi < 4; ++mi) {
#pragma unroll
        for (int ni = 0; ni < NFR; ++ni) {
#pragma unroll
            for (int j = 0; j < 4; ++j) {
                int row = mblk + m0w + mi * 16 + lg * 4 + j;
                int col = nblk + n0w + ni * 16 + lq;
                float val = acc[mi][ni][j];
                if (OUT_BF16)
                    ((u16*)C)[(size_t)row * N + col] = f2bf(val);
                else
                    ((float*)C)[(size_t)row * N + col] = val;
            }
        }
    }
}

// ---------------- attention tile compute (one 16q x 64k tile for one wave)
// Constant-shift softmax (shift-invariant, scores bounded): no max tracking.
// PV via 16x16x16 MFMA: A-frag = own cvt_pk'd P words, zero cross-lane exchange.
template <bool DIAG>
__device__ __forceinline__ void attn_tile(const u16 (*__restrict__ Kt)[72],
                                          const u16 (*__restrict__ Vt)[72],
                                          const short8v* __restrict__ qf,
                                          f32x4* __restrict__ o,
                                          float& l_r,
                                          int lq, int lg, int w4, int kt64, int qg) {
    const float CLOG = 0.18033688011112042f;   // log2(e)/sqrt(64)
    const float MOFF = 11.541560327111707f;    // 8*log2(e)
    int ksmax = DIAG ? w4 : 3;
    f32x4 st[4] = {};
    __builtin_amdgcn_s_setprio(1);
#pragma unroll
    for (int ks = 0; ks < 4; ++ks) {
        if (ks <= ksmax) {
            short8v a0 = *reinterpret_cast<const short8v*>(&Kt[ks * 16 + lq][lg * 8]);
            short8v a1 = *reinterpret_cast<const short8v*>(&Kt[ks * 16 + lq][32 + lg * 8]);
            st[ks] = __builtin_amdgcn_mfma_f32_16x16x32_bf16(a0, qf[0], st[ks], 0, 0, 0);
            st[ks] = __builtin_amdgcn_mfma_f32_16x16x32_bf16(a1, qf[1], st[ks], 0, 0, 0);
        }
    }
    __builtin_amdgcn_s_setprio(0);
    float p[4][4];
    float psum = 0.f;
#pragma unroll
    for (int ks = 0; ks < 4; ++ks)
#pragma unroll
        for (int j = 0; j < 4; ++j) {
            float v = st[ks][j];
            if (DIAG) {
                int kg = kt64 + ks * 16 + lg * 4 + j;
                v = (ks <= ksmax && kg <= qg) ? v : -INFINITY;
            }
            float pv = exp2f(fmaf(v, CLOG, -MOFF));
            p[ks][j] = pv;
            psum += pv;
        }
    l_r += psum;
    union { u32 w2[2]; short4v v; } pa[4];
#pragma unroll
    for (int ks = 0; ks < 4; ++ks) {
        pa[ks].w2[0] = cvt_pk_bf16(p[ks][0], p[ks][1]);
        pa[ks].w2[1] = cvt_pk_bf16(p[ks][2], p[ks][3]);
    }
    __builtin_amdgcn_s_setprio(1);
#pragma unroll
    for (int ni = 0; ni < 4; ++ni) {
        int d = ni * 16 + lq;
        int sw = ((d >> 3) & 7) << 3;
        const u16* vrow = Vt[d];
#pragma unroll
        for (int ks = 0; ks < 4; ++ks) {
            if (ks <= ksmax) {
                short4v vb = *reinterpret_cast<const short4v*>(&vrow[(ks * 16 + lg * 4) ^ sw]);
                o[ni] = __builtin_amdgcn_mfma_f32_16x16x16bf16_1k(pa[ks].v, vb, o[ni], 0, 0, 0);
            }
        }
    }
    __builtin_amdgcn_s_setprio(0);
}

// ---------------- flash attention, causal, balanced dual q-tile blocks, 8 waves.
// grid (8, 64), 512 threads. Waves 0-3: lo qblk tiles; waves 4-7: hi qblk tiles.
__global__ __launch_bounds__(512) void attn_kernel(const u16* __restrict__ qkv,
                                                   u16* __restrict__ out) {
    int tid = threadIdx.x;
    int lane = tid & 63, wid = tid >> 6;
    int lq = lane & 15, lg = lane >> 4;
    int w4 = wid & 3;
    bool is_hi = wid >= 4;
    int bh = blockIdx.y;
    int b = bh >> 4, h = bh & 15;
    int qlo_blk = blockIdx.x;
    int qhi_blk = 15 - qlo_blk;
    int myblk = is_hi ? qhi_blk : qlo_blk;
    int qt = myblk * 64 + w4 * 16;

    const u16* base = qkv + (size_t)b * T_SEQ * THREE_E;
    const u16* Qb = base + h * HD;
    const u16* Kb = base + E_DIM + h * HD;

    __shared__ __align__(16) u16 Kt[2][64][72];
    __shared__ __align__(16) u16 Vt[2][64][72];

    short8v qf[2];
    {
        const u16* qr = Qb + (size_t)(qt + lq) * THREE_E + lg * 8;
        qf[0] = *reinterpret_cast<const short8v*>(qr);
        qf[1] = *reinterpret_cast<const short8v*>(qr + 32);
    }
    f32x4 o[4] = {};
    float l_r = 0.f;
    int qg = qt + lq;

    int row_s = tid >> 3, c8 = tid & 7;   // 512 threads -> rows 0..63, one 16B each
    short8v kreg, vreg;

    // prologue: stage tile 0 into buf0, prefetch tile 1
    {
        const u16* src = Kb + (size_t)row_s * THREE_E + c8 * 8;
        kreg = *reinterpret_cast<const short8v*>(src);
        vreg = *reinterpret_cast<const short8v*>(src + E_DIM);
    }
    {
        *reinterpret_cast<short8v*>(&Kt[0][row_s][c8 * 8]) = kreg;
        int rs = row_s ^ (c8 << 3);
#pragma unroll
        for (int e = 0; e < 8; ++e) Vt[0][c8 * 8 + e][rs] = (u16)vreg[e];
    }
    if (qhi_blk >= 1) {
        const u16* src = Kb + (size_t)(64 + row_s) * THREE_E + c8 * 8;
        kreg = *reinterpret_cast<const short8v*>(src);
        vreg = *reinterpret_cast<const short8v*>(src + E_DIM);
    }
    __syncthreads();

    for (int kt = 0; kt <= qhi_blk; ++kt) {
        int cur = kt & 1;
        if (kt < qhi_blk) {
            *reinterpret_cast<short8v*>(&Kt[cur ^ 1][row_s][c8 * 8]) = kreg;
            int rs = row_s ^ (c8 << 3);
#pragma unroll
            for (int e = 0; e < 8; ++e) Vt[cur ^ 1][c8 * 8 + e][rs] = (u16)vreg[e];
            if (kt + 1 < qhi_blk) {
                const u16* src = Kb + (size_t)((kt + 2) * 64 + row_s) * THREE_E + c8 * 8;
                kreg = *reinterpret_cast<const short8v*>(src);
                vreg = *reinterpret_cast<const short8v*>(src + E_DIM);
            }
        }
        if (is_hi) {
            if (kt < qhi_blk)
                attn_tile<false>(Kt[cur], Vt[cur], qf, o, l_r, lq, lg, w4, kt * 64, qg);
            else
                attn_tile<true>(Kt[cur], Vt[cur], qf, o, l_r, lq, lg, w4, kt * 64, qg);
        } else {
            if (kt < qlo_blk)
                attn_tile<false>(Kt[cur], Vt[cur], qf, o, l_r, lq, lg, w4, kt * 64, qg);
            else if (kt == qlo_blk)
                attn_tile<true>(Kt[cur], Vt[cur], qf, o, l_r, lq, lg, w4, kt * 64, qg);
        }
        __syncthreads();
    }
    // epilogue: reduce l across the 4 lanes sharing lq, normalize, store bf16
    float lf = l_r;
    lf += __shfl_xor(lf, 16); lf += __shfl_xor(lf, 32);
#pragma unroll
    for (int j = 0; j < 4; ++j) {
        float linv = 1.0f / __shfl(lf, lg * 4 + j);
        size_t row = (size_t)b * T_SEQ + qt + lg * 4 + j;
#pragma unroll
        for (int ni = 0; ni < 4; ++ni)
            out[row * E_DIM + h * HD + ni * 16 + lq] = f2bf(o[ni][j] * linv);
    }
}

// ---------------- launch
extern "C" void kernel_launch(void* const* d_in, const int* in_sizes, int n_in,
                              void* d_out, int out_size, void* d_ws, size_t ws_size,
                              hipStream_t stream) {
    const float* x = (const float*)d_in[0];
    const float* scale = (const float*)d_in[1];
    const float* w_qkv = (const float*)d_in[2];
    const float* w_proj = (const float*)d_in[3];
    float* out = (float*)d_out;

    char* ws = (char*)d_ws;
    u16* xn   = (u16*)(ws);                    // 8 MB
    u16* wqb  = (u16*)(ws + (8ull << 20));     // 6 MB
    u16* wpb  = (u16*)(ws + (14ull << 20));    // 2 MB
    u16* qkv  = (u16*)(ws + (16ull << 20));    // 24 MB
    u16* aout = (u16*)(ws + (40ull << 20));    // 8 MB

    prep_kernel<<<dim3(8192), dim3(256), 0, stream>>>(x, scale, w_qkv, w_proj, xn, wqb, wpb);
    gemm_lds_kernel<64, true><<<dim3(THREE_E / 64, NTOK / 128), dim3(256), 0, stream>>>(
        xn, wqb, (void*)qkv, THREE_E, E_DIM);
    attn_kernel<<<dim3(8, B_SZ * NH), dim3(512), 0, stream>>>(qkv, aout);
    gemm_lds_kernel<64, false><<<dim3(E_DIM / 64, NTOK / 128), dim3(256), 0, stream>>>(
        aout, wpb, (void*)out, E_DIM, E_DIM);
}

// Round 22
// 85.231 us; speedup vs baseline: 1.0881x; 1.0881x over previous
//
#include <hip/hip_runtime.h>
#include <hip/hip_bf16.h>
#include <stdint.h>

#define B_SZ 4
#define T_SEQ 1024
#define E_DIM 1024
#define NH 16
#define HD 64
#define THREE_E 3072
#define NTOK 4096

typedef unsigned short u16;
typedef unsigned int u32;
using short8v = __attribute__((ext_vector_type(8))) short;
using short4v = __attribute__((ext_vector_type(4))) short;
using f32x4 = __attribute__((ext_vector_type(4))) float;

__device__ __forceinline__ u16 f2bf(float f) {
    union { float f; uint32_t u; } c; c.f = f;
    uint32_t u = c.u;
    uint32_t r = (u + 0x7FFFu + ((u >> 16) & 1u)) >> 16;
    return (u16)r;
}

__device__ __forceinline__ u32 cvt_pk_bf16(float lo, float hi) {
    u32 r;
    asm("v_cvt_pk_bf16_f32 %0, %1, %2" : "=v"(r) : "v"(lo), "v"(hi));
    return r;
}

__device__ __forceinline__ void gload_lds16(const u16* g, u16* l) {
    __builtin_amdgcn_global_load_lds((const __attribute__((address_space(1))) void*)g,
                                     (__attribute__((address_space(3))) void*)l, 16, 0, 0);
}

// ---------------- fused prep: RMSNorm (blocks 0..4095) + weight cast (4096..8191)
__global__ __launch_bounds__(256) void prep_kernel(const float* __restrict__ x,
                                                   const float* __restrict__ scale,
                                                   const float* __restrict__ wq,
                                                   const float* __restrict__ wp,
                                                   u16* __restrict__ xn,
                                                   u16* __restrict__ wqb,
                                                   u16* __restrict__ wpb) {
    int bx = blockIdx.x;
    int tid = threadIdx.x;
    if (bx < 4096) {
        int row = bx;
        const float4* xr = reinterpret_cast<const float4*>(x + (size_t)row * E_DIM);
        float4 v = xr[tid];
        float ss = v.x * v.x + v.y * v.y + v.z * v.z + v.w * v.w;
        for (int off = 32; off > 0; off >>= 1) ss += __shfl_xor(ss, off);
        __shared__ float red[4];
        if ((tid & 63) == 0) red[tid >> 6] = ss;
        __syncthreads();
        float total = red[0] + red[1] + red[2] + red[3];
        float rs = rsqrtf(total * (1.0f / E_DIM) + 1e-5f);
        float4 s = reinterpret_cast<const float4*>(scale)[tid];
        u16* o = xn + (size_t)row * E_DIM + tid * 4;
        o[0] = f2bf(v.x * rs * s.x);
        o[1] = f2bf(v.y * rs * s.y);
        o[2] = f2bf(v.z * rs * s.z);
        o[3] = f2bf(v.w * rs * s.w);
    } else {
        const int NQ = (THREE_E * E_DIM) / 4;
        const int NP = (E_DIM * E_DIM) / 4;
        int i = (bx - 4096) * 256 + tid;
        if (i < NQ) {
            float4 v = reinterpret_cast<const float4*>(wq)[i];
            u16* o = wqb + (size_t)i * 4;
            o[0] = f2bf(v.x); o[1] = f2bf(v.y); o[2] = f2bf(v.z); o[3] = f2bf(v.w);
        } else if (i < NQ + NP) {
            int j = i - NQ;
            float4 v = reinterpret_cast<const float4*>(wp)[j];
            u16* o = wpb + (size_t)j * 4;
            o[0] = f2bf(v.x); o[1] = f2bf(v.y); o[2] = f2bf(v.z); o[3] = f2bf(v.w);
        }
    }
}

// ---------------- 2-phase GEMM + T3-minimum async prefetch.
// Per iter: barrier(drains stage(t)); ds_reads(t); barrier(drains reads);
// stage(t+1) into SAME buffer (overlaps MFMA cluster); all MFMAs.
template <int BN, bool OUT_BF16>
__global__ __launch_bounds__(256) void gemm_lds_kernel(const u16* __restrict__ A,
                                                       const u16* __restrict__ Bw,
                                                       void* __restrict__ C,
                                                       int N, int K) {
    constexpr int NFR = BN / 32;
    __shared__ u16 As[128 * 64];
    __shared__ u16 Bs[BN * 64];
    int tid = threadIdx.x;
    int lane = tid & 63, wid = tid >> 6;
    int lq = lane & 15, lg = lane >> 4;

    int gx = gridDim.x;
    int nwg = gx * gridDim.y;
    int orig = blockIdx.y * gx + blockIdx.x;
    int cpx = nwg >> 3;
    int swz = (orig & 7) * cpx + (orig >> 3);
    int bx = swz % gx, by = swz / gx;
    int mblk = by * 128, nblk = bx * BN;

    int srowA = wid * 32 + (lane >> 3);
    int srowB = wid * (BN / 4) + (lane >> 3);
    int csw = ((lane & 7) ^ ((lane >> 3) & 7)) * 8;
    const u16* gA = A + (size_t)(mblk + srowA) * K + csw;
    const u16* gB = Bw + (size_t)(nblk + srowB) * K + csw;
    u16* lA = As + wid * 2048;
    u16* lB = Bs + wid * (BN / 4) * 64;

    f32x4 acc[4][NFR] = {};
    int m0w = (wid >> 1) * 64;
    int n0w = (wid & 1) * (BN / 2);
    int r7 = lq & 7;
    const int NT = K / 64;

#pragma unroll
    for (int i = 0; i < 4; ++i) gload_lds16(gA + (size_t)i * 8 * K, lA + i * 512);
#pragma unroll
    for (int i = 0; i < NFR; ++i) gload_lds16(gB + (size_t)i * 8 * K, lB + i * 512);

    for (int t = 0; t < NT; ++t) {
        __syncthreads();   // implicit vmcnt(0): stage(t) landed (all waves)
        short8v af[2][4], bf[2][NFR];
#pragma unroll
        for (int kk = 0; kk < 2; ++kk) {
#pragma unroll
            for (int mi = 0; mi < 4; ++mi)
                af[kk][mi] = *reinterpret_cast<const short8v*>(
                    &As[(m0w + mi * 16 + lq) * 64 + ((kk * 4 + lg) ^ r7) * 8]);
#pragma unroll
            for (int ni = 0; ni < NFR; ++ni)
                bf[kk][ni] = *reinterpret_cast<const short8v*>(
                    &Bs[(n0w + ni * 16 + lq) * 64 + ((kk * 4 + lg) ^ r7) * 8]);
        }
        __syncthreads();   // implicit lgkmcnt(0): all waves done reading tile t
        if (t + 1 < NT) {  // async stage of t+1 overlaps the MFMA cluster below
            int k0 = (t + 1) * 64;
#pragma unroll
            for (int i = 0; i < 4; ++i) gload_lds16(gA + k0 + (size_t)i * 8 * K, lA + i * 512);
#pragma unroll
            for (int i = 0; i < NFR; ++i) gload_lds16(gB + k0 + (size_t)i * 8 * K, lB + i * 512);
        }
        __builtin_amdgcn_sched_barrier(0);   // pin stage issue above the MFMAs
        __builtin_amdgcn_s_setprio(1);
#pragma unroll
        for (int mi = 0; mi < 4; ++mi)
#pragma unroll
            for (int ni = 0; ni < NFR; ++ni) {
                acc[mi][ni] = __builtin_amdgcn_mfma_f32_16x16x32_bf16(af[0][mi], bf[0][ni], acc[mi][ni], 0, 0, 0);
                acc[mi][ni] = __builtin_amdgcn_mfma_f32_16x16x32_bf16(af[1][mi], bf[1][ni], acc[mi][ni], 0, 0, 0);
            }
        __builtin_amdgcn_s_setprio(0);
    }
#pragma unroll
    for (int mi = 0; mi < 4; ++mi) {
#pragma unroll
        for (int ni = 0; ni < NFR; ++ni) {
#pragma unroll
            for (int j = 0; j < 4; ++j) {
                int row = mblk + m0w + mi * 16 + lg * 4 + j;
                int col = nblk + n0w + ni * 16 + lq;
                float val = acc[mi][ni][j];
                if (OUT_BF16)
                    ((u16*)C)[(size_t)row * N + col] = f2bf(val);
                else
                    ((float*)C)[(size_t)row * N + col] = val;
            }
        }
    }
}

// ---------------- attention tile compute (one 16q x 64k tile for one wave)
// Constant-shift softmax (shift-invariant, scores bounded): no max tracking.
// PV via 16x16x16 MFMA: A-frag = own cvt_pk'd P words, zero cross-lane exchange.
template <bool DIAG>
__device__ __forceinline__ void attn_tile(const u16 (*__restrict__ Kt)[72],
                                          const u16 (*__restrict__ Vt)[72],
                                          const short8v* __restrict__ qf,
                                          f32x4* __restrict__ o,
                                          float& l_r,
                                          int lq, int lg, int w4, int kt64, int qg) {
    const float CLOG = 0.18033688011112042f;   // log2(e)/sqrt(64)
    const float MOFF = 11.541560327111707f;    // 8*log2(e)
    int ksmax = DIAG ? w4 : 3;
    f32x4 st[4] = {};
    __builtin_amdgcn_s_setprio(1);
#pragma unroll
    for (int ks = 0; ks < 4; ++ks) {
        if (ks <= ksmax) {
            short8v a0 = *reinterpret_cast<const short8v*>(&Kt[ks * 16 + lq][lg * 8]);
            short8v a1 = *reinterpret_cast<const short8v*>(&Kt[ks * 16 + lq][32 + lg * 8]);
            st[ks] = __builtin_amdgcn_mfma_f32_16x16x32_bf16(a0, qf[0], st[ks], 0, 0, 0);
            st[ks] = __builtin_amdgcn_mfma_f32_16x16x32_bf16(a1, qf[1], st[ks], 0, 0, 0);
        }
    }
    __builtin_amdgcn_s_setprio(0);
    float p[4][4];
    float psum = 0.f;
#pragma unroll
    for (int ks = 0; ks < 4; ++ks)
#pragma unroll
        for (int j = 0; j < 4; ++j) {
            float v = st[ks][j];
            if (DIAG) {
                int kg = kt64 + ks * 16 + lg * 4 + j;
                v = (ks <= ksmax && kg <= qg) ? v : -INFINITY;
            }
            float pv = exp2f(fmaf(v, CLOG, -MOFF));
            p[ks][j] = pv;
            psum += pv;
        }
    l_r += psum;
    union { u32 w2[2]; short4v v; } pa[4];
#pragma unroll
    for (int ks = 0; ks < 4; ++ks) {
        pa[ks].w2[0] = cvt_pk_bf16(p[ks][0], p[ks][1]);
        pa[ks].w2[1] = cvt_pk_bf16(p[ks][2], p[ks][3]);
    }
    __builtin_amdgcn_s_setprio(1);
#pragma unroll
    for (int ni = 0; ni < 4; ++ni) {
        int d = ni * 16 + lq;
        int sw = ((d >> 3) & 7) << 3;
        const u16* vrow = Vt[d];
#pragma unroll
        for (int ks = 0; ks < 4; ++ks) {
            if (ks <= ksmax) {
                short4v vb = *reinterpret_cast<const short4v*>(&vrow[(ks * 16 + lg * 4) ^ sw]);
                o[ni] = __builtin_amdgcn_mfma_f32_16x16x16bf16_1k(pa[ks].v, vb, o[ni], 0, 0, 0);
            }
        }
    }
    __builtin_amdgcn_s_setprio(0);
}

// ---------------- flash attention, causal, balanced dual q-tile blocks, 8 waves.
// grid (8, 64), 512 threads. Waves 0-3: lo qblk tiles; waves 4-7: hi qblk tiles.
__global__ __launch_bounds__(512) void attn_kernel(const u16* __restrict__ qkv,
                                                   u16* __restrict__ out) {
    int tid = threadIdx.x;
    int lane = tid & 63, wid = tid >> 6;
    int lq = lane & 15, lg = lane >> 4;
    int w4 = wid & 3;
    bool is_hi = wid >= 4;
    int bh = blockIdx.y;
    int b = bh >> 4, h = bh & 15;
    int qlo_blk = blockIdx.x;
    int qhi_blk = 15 - qlo_blk;
    int myblk = is_hi ? qhi_blk : qlo_blk;
    int qt = myblk * 64 + w4 * 16;

    const u16* base = qkv + (size_t)b * T_SEQ * THREE_E;
    const u16* Qb = base + h * HD;
    const u16* Kb = base + E_DIM + h * HD;

    __shared__ __align__(16) u16 Kt[2][64][72];
    __shared__ __align__(16) u16 Vt[2][64][72];

    short8v qf[2];
    {
        const u16* qr = Qb + (size_t)(qt + lq) * THREE_E + lg * 8;
        qf[0] = *reinterpret_cast<const short8v*>(qr);
        qf[1] = *reinterpret_cast<const short8v*>(qr + 32);
    }
    f32x4 o[4] = {};
    float l_r = 0.f;
    int qg = qt + lq;

    int row_s = tid >> 3, c8 = tid & 7;   // 512 threads -> rows 0..63, one 16B each
    short8v kreg, vreg;

    // prologue: stage tile 0 into buf0, prefetch tile 1
    {
        const u16* src = Kb + (size_t)row_s * THREE_E + c8 * 8;
        kreg = *reinterpret_cast<const short8v*>(src);
        vreg = *reinterpret_cast<const short8v*>(src + E_DIM);
    }
    {
        *reinterpret_cast<short8v*>(&Kt[0][row_s][c8 * 8]) = kreg;
        int rs = row_s ^ (c8 << 3);
#pragma unroll
        for (int e = 0; e < 8; ++e) Vt[0][c8 * 8 + e][rs] = (u16)vreg[e];
    }
    if (qhi_blk >= 1) {
        const u16* src = Kb + (size_t)(64 + row_s) * THREE_E + c8 * 8;
        kreg = *reinterpret_cast<const short8v*>(src);
        vreg = *reinterpret_cast<const short8v*>(src + E_DIM);
    }
    __syncthreads();

    for (int kt = 0; kt <= qhi_blk; ++kt) {
        int cur = kt & 1;
        if (kt < qhi_blk) {
            *reinterpret_cast<short8v*>(&Kt[cur ^ 1][row_s][c8 * 8]) = kreg;
            int rs = row_s ^ (c8 << 3);
#pragma unroll
            for (int e = 0; e < 8; ++e) Vt[cur ^ 1][c8 * 8 + e][rs] = (u16)vreg[e];
            if (kt + 1 < qhi_blk) {
                const u16* src = Kb + (size_t)((kt + 2) * 64 + row_s) * THREE_E + c8 * 8;
                kreg = *reinterpret_cast<const short8v*>(src);
                vreg = *reinterpret_cast<const short8v*>(src + E_DIM);
            }
        }
        if (is_hi) {
            if (kt < qhi_blk)
                attn_tile<false>(Kt[cur], Vt[cur], qf, o, l_r, lq, lg, w4, kt * 64, qg);
            else
                attn_tile<true>(Kt[cur], Vt[cur], qf, o, l_r, lq, lg, w4, kt * 64, qg);
        } else {
            if (kt < qlo_blk)
                attn_tile<false>(Kt[cur], Vt[cur], qf, o, l_r, lq, lg, w4, kt * 64, qg);
            else if (kt == qlo_blk)
                attn_tile<true>(Kt[cur], Vt[cur], qf, o, l_r, lq, lg, w4, kt * 64, qg);
        }
        __syncthreads();
    }
    // epilogue: reduce l across the 4 lanes sharing lq, normalize, store bf16
    float lf = l_r;
    lf += __shfl_xor(lf, 16); lf += __shfl_xor(lf, 32);
#pragma unroll
    for (int j = 0; j < 4; ++j) {
        float linv = 1.0f / __shfl(lf, lg * 4 + j);
        size_t row = (size_t)b * T_SEQ + qt + lg * 4 + j;
#pragma unroll
        for (int ni = 0; ni < 4; ++ni)
            out[row * E_DIM + h * HD + ni * 16 + lq] = f2bf(o[ni][j] * linv);
    }
}

// ---------------- launch
extern "C" void kernel_launch(void* const* d_in, const int* in_sizes, int n_in,
                              void* d_out, int out_size, void* d_ws, size_t ws_size,
                              hipStream_t stream) {
    const float* x = (const float*)d_in[0];
    const float* scale = (const float*)d_in[1];
    const float* w_qkv = (const float*)d_in[2];
    const float* w_proj = (const float*)d_in[3];
    float* out = (float*)d_out;

    char* ws = (char*)d_ws;
    u16* xn   = (u16*)(ws);                    // 8 MB
    u16* wqb  = (u16*)(ws + (8ull << 20));     // 6 MB
    u16* wpb  = (u16*)(ws + (14ull << 20));    // 2 MB
    u16* qkv  = (u16*)(ws + (16ull << 20));    // 24 MB
    u16* aout = (u16*)(ws + (40ull << 20));    // 8 MB

    prep_kernel<<<dim3(8192), dim3(256), 0, stream>>>(x, scale, w_qkv, w_proj, xn, wqb, wpb);
    gemm_lds_kernel<128, true><<<dim3(THREE_E / 128, NTOK / 128), dim3(256), 0, stream>>>(
        xn, wqb, (void*)qkv, THREE_E, E_DIM);
    attn_kernel<<<dim3(8, B_SZ * NH), dim3(512), 0, stream>>>(qkv, aout);
    gemm_lds_kernel<64, false><<<dim3(E_DIM / 64, NTOK / 128), dim3(256), 0, stream>>>(
        aout, wpb, (void*)out, E_DIM, E_DIM);
}